// Round 6
// baseline (63.127 us; speedup 1.0000x reference)
//
#include <hip/hip_runtime.h>
#include <math.h>

#define N_BOX 8192
#define NT 1024
#define MAX_TOPK 128
#define IOU_THR 0.3f
#define M_TARGET 400u
#define CAP 1024
#define BIN_SHIFT 19      // top 13 bits -> 8192 bins

// ---- ws layout ----
#define WS_BOXES_OFF 0                                  // 128 KB float4[8192]
#define WS_KEYS_OFF  (N_BOX * 16)                       // 32 KB  u32[8192]
#define WS_CAND_OFF  (WS_KEYS_OFF + N_BOX * 4)          // 8 KB   u64[CAP]
#define WS_SORT_OFF  (WS_CAND_OFF + CAP * 8)            // 8 KB   u64[CAP]
#define WS_SBOX_OFF  (WS_SORT_OFF + CAP * 8)            // 16 KB  float4[CAP]
#define WS_KEEP_OFF  (WS_SBOX_OFF + CAP * 16)           // 512 B  int[MAX_TOPK]
#define WS_META_OFF  (WS_KEEP_OFF + MAX_TOPK * 4)       // int[2]: C, nkept

// ---------------- K1: decode + 32-bit sort-key build ----------------
__global__ void decode_kernel(const float* __restrict__ x,
                              const float* __restrict__ y,
                              const float* __restrict__ anchors,
                              float4* __restrict__ boxes,
                              unsigned* __restrict__ keys)
{
#pragma clang fp contract(off)
    int i = blockIdx.x * blockDim.x + threadIdx.x;
    if (i >= N_BOX) return;

    float s = 1.0f / (1.0f + expf(-x[i]));
    unsigned k32 = ~(__float_as_uint(s) | 0x80000000u);   // asc key = desc score
    keys[i] = k32;

    const float inv128 = 0.0078125f;
    const float2* yr = (const float2*)(y + i * 18);
    float2 ya = yr[0];
    float2 yb = yr[1];
    float2 an = ((const float2*)anchors)[i];
    float cx = ya.x * inv128 + an.x;
    float cy = ya.y * inv128 + an.y;
    float w2 = (yb.x * inv128) * 0.5f;
    float h2 = (yb.y * inv128) * 0.5f;
    boxes[i] = make_float4(cx - w2, cy - h2, cx + w2, cy + h2);
}

// ---------------- K2a: histogram + scan + compact ----------------
__global__ __launch_bounds__(NT)
void select_kernel(const unsigned* __restrict__ keys,
                   unsigned long long* __restrict__ g_cand,
                   int* __restrict__ g_meta)
{
    __shared__ unsigned s_hist[N_BOX];              // 32 KB
    __shared__ unsigned s_waveexcl[17];
    __shared__ unsigned long long s_cand[CAP];      // 8 KB
    __shared__ int s_cnt, s_B, s_C;

    const int tid = threadIdx.x;
    const int lane = tid & 63;
    const int wv = tid >> 6;

    const uint4* kp = (const uint4*)keys;
    uint4 ka = kp[tid * 2 + 0];
    uint4 kb = kp[tid * 2 + 1];
    unsigned myk[8] = {ka.x, ka.y, ka.z, ka.w, kb.x, kb.y, kb.z, kb.w};

    if (tid == 0) s_cnt = 0;
    {
        uint4 z = make_uint4(0u, 0u, 0u, 0u);
        uint4* hp = (uint4*)s_hist;
        hp[tid * 2 + 0] = z;
        hp[tid * 2 + 1] = z;
        s_cand[tid] = ~0ull;
    }
    __syncthreads();

#pragma unroll
    for (int k = 0; k < 8; k++)
        atomicAdd(&s_hist[myk[k] >> BIN_SHIFT], 1u);
    __syncthreads();

    uint4 h0 = ((const uint4*)s_hist)[tid * 2 + 0];
    uint4 h1 = ((const uint4*)s_hist)[tid * 2 + 1];
    unsigned binv[8] = {h0.x, h0.y, h0.z, h0.w, h1.x, h1.y, h1.z, h1.w};
    unsigned csum = binv[0] + binv[1] + binv[2] + binv[3]
                  + binv[4] + binv[5] + binv[6] + binv[7];

    unsigned incl = csum;
    for (int off = 1; off < 64; off <<= 1) {
        unsigned n = __shfl_up(incl, off);
        if (lane >= off) incl += n;
    }
    if (lane == 63) s_waveexcl[wv + 1] = incl;
    __syncthreads();
    if (wv == 0) {
        unsigned t = (lane < 16) ? s_waveexcl[lane + 1] : 0u;
        unsigned v = t;
        for (int off = 1; off < 16; off <<= 1) {
            unsigned n = __shfl_up(v, off);
            if (lane >= off) v += n;
        }
        if (lane < 16) s_waveexcl[lane] = v - t;
    }
    __syncthreads();

    unsigned myexcl = s_waveexcl[wv] + incl - csum;
    if (myexcl < M_TARGET && myexcl + csum >= M_TARGET) {
        unsigned run = myexcl;
#pragma unroll
        for (int k = 0; k < 8; k++) {
            run += binv[k];
            if (run >= M_TARGET) { s_B = tid * 8 + k; s_C = (int)run; break; }
        }
    }
    __syncthreads();

    const int B = s_B;
#pragma unroll
    for (int k = 0; k < 8; k++) {
        if ((int)(myk[k] >> BIN_SHIFT) <= B) {
            int p = atomicAdd(&s_cnt, 1);
            if (p < CAP)
                s_cand[p] = (((unsigned long long)myk[k]) << 32) | (unsigned)(tid * 8 + k);
        }
    }
    __syncthreads();

    g_cand[tid] = s_cand[tid];
    if (tid == 0) {
        int C = s_C; if (C > CAP) C = CAP;
        g_meta[0] = C;
    }
}

// ---------------- K2b: rank sort + box gather ----------------
__global__ __launch_bounds__(NT)
void sortgather_kernel(const unsigned long long* __restrict__ g_cand,
                       const float4* __restrict__ boxes,
                       unsigned long long* __restrict__ g_sorted,
                       float4* __restrict__ g_sbox,
                       const int* __restrict__ g_meta)
{
    __shared__ unsigned long long s_cand[CAP];      // 8 KB
    __shared__ unsigned long long s_sorted[CAP];    // 8 KB

    const int tid = threadIdx.x;
    const int C = g_meta[0];

    s_cand[tid] = g_cand[tid];
    __syncthreads();

    const int Cpad = (C + 7) & ~7;
    if (tid < C) {
        unsigned long long me = s_cand[tid];
        int rank = 0;
        const ulonglong2* cp = (const ulonglong2*)s_cand;
        for (int j = 0; j < Cpad; j += 8) {
            ulonglong2 a = cp[(j >> 1) + 0];
            ulonglong2 b = cp[(j >> 1) + 1];
            ulonglong2 d = cp[(j >> 1) + 2];
            ulonglong2 e = cp[(j >> 1) + 3];
            rank += (a.x < me) + (a.y < me) + (b.x < me) + (b.y < me)
                  + (d.x < me) + (d.y < me) + (e.x < me) + (e.y < me);
        }
        s_sorted[rank] = me;
    }
    __syncthreads();

    if (tid < C) {
        unsigned long long kk = s_sorted[tid];
        int idx = (int)(unsigned)(kk & 0xFFFFFFFFull);
        g_sorted[tid] = kk;
        g_sbox[tid] = boxes[idx];
    }
}

// ---------------- K2c: single-wave NMS ----------------
__global__ __launch_bounds__(64)
void nms_kernel(const unsigned long long* __restrict__ g_sorted,
                const float4* __restrict__ g_sbox,
                int* __restrict__ g_keep,
                int* __restrict__ g_meta,
                int top_k)
{
#pragma clang fp contract(off)
    const int lane = threadIdx.x;
    const int C = g_meta[0];

    float k0x1 = 0.f, k0y1 = 0.f, k0x2 = 0.f, k0y2 = 0.f, k0a = 0.f;  // slot = lane
    float k1x1 = 0.f, k1y1 = 0.f, k1x2 = 0.f, k1y2 = 0.f, k1a = 0.f;  // slot = lane+64
    int nkept = 0;
    int base = 0;
    float4 bb = make_float4(0.f, 0.f, 0.f, 0.f);
    int bidx = 0;
    if (lane < C) {
        bb = g_sbox[lane];
        bidx = (int)(unsigned)(g_sorted[lane] & 0xFFFFFFFFull);
    }

    int c = 0;
    while (c < C && nkept < top_k) {
        int p = c - base;
        if (p == 64) {
            base += 64; p = 0;
            int g = base + lane;
            if (g < C) {
                bb = g_sbox[g];
                bidx = (int)(unsigned)(g_sorted[g] & 0xFFFFFFFFull);
            }
        }
        float cx1 = __shfl(bb.x, p);
        float cy1 = __shfl(bb.y, p);
        float cx2 = __shfl(bb.z, p);
        float cy2 = __shfl(bb.w, p);
        int  cidx = __shfl(bidx, p);
        float carea = (cx2 - cx1) * (cy2 - cy1);

        bool hit = false;
        if (lane < nkept) {
            float iw = fmaxf(fminf(k0x2, cx2) - fmaxf(k0x1, cx1), 0.0f);
            float ih = fmaxf(fminf(k0y2, cy2) - fmaxf(k0y1, cy1), 0.0f);
            float inter = iw * ih;
            float iou = inter / (k0a + carea - inter);
            if (iou > IOU_THR) hit = true;
        }
        if (lane + 64 < nkept) {
            float iw = fmaxf(fminf(k1x2, cx2) - fmaxf(k1x1, cx1), 0.0f);
            float ih = fmaxf(fminf(k1y2, cy2) - fmaxf(k1y1, cy1), 0.0f);
            float inter = iw * ih;
            float iou = inter / (k1a + carea - inter);
            if (iou > IOU_THR) hit = true;
        }
        unsigned long long m = __ballot(hit);
        if (m == 0ull) {
            if (nkept < 64) {
                if (lane == nkept) {
                    k0x1 = cx1; k0y1 = cy1; k0x2 = cx2; k0y2 = cy2; k0a = carea;
                }
            } else {
                if (lane == nkept - 64) {
                    k1x1 = cx1; k1y1 = cy1; k1x2 = cx2; k1y2 = cy2; k1a = carea;
                }
            }
            if (lane == 0) g_keep[nkept] = cidx;
            nkept++;
        }
        c++;
    }
    if (lane == 0) g_meta[1] = nkept;
}

// ---------------- K2d: output gather ----------------
__global__ __launch_bounds__(NT)
void output_kernel(const float* __restrict__ x,
                   const float* __restrict__ y,
                   const float* __restrict__ anchors,
                   const int* __restrict__ g_keep,
                   const int* __restrict__ g_meta,
                   float* __restrict__ out,
                   int top_k)
{
#pragma clang fp contract(off)
    const int t = threadIdx.x;
    const int total = top_k * 8;
    if (t >= total) return;

    const int nkept = g_meta[1];
    const float inv128 = 0.0078125f;
    int r = t >> 3;
    int col = t & 7;
    float v = 0.0f;
    if (r < nkept) {
        int idx = g_keep[r];
        if (col == 0) {
            v = 1.0f / (1.0f + expf(-x[idx]));
        } else {
            int j = (col <= 3) ? (col - 1) : ((col <= 5) ? col : (col + 2));
            float a;
            if (j == 2) a = 0.0f;
            else        a = (j & 1) ? anchors[idx * 2 + 1] : anchors[idx * 2 + 0];
            v = y[idx * 18 + j] * inv128 + a;
        }
    }
    out[t] = v;
}

extern "C" void kernel_launch(void* const* d_in, const int* in_sizes, int n_in,
                              void* d_out, int out_size, void* d_ws, size_t ws_size,
                              hipStream_t stream) {
    const float* x       = (const float*)d_in[0];   // (1, 8192, 1)
    const float* y       = (const float*)d_in[1];   // (1, 8192, 18)
    const float* anchors = (const float*)d_in[2];   // (8192, 2)
    float* out = (float*)d_out;                     // (top_k, 8) f32

    char* ws = (char*)d_ws;
    float4* boxes              = (float4*)(ws + WS_BOXES_OFF);
    unsigned* keys             = (unsigned*)(ws + WS_KEYS_OFF);
    unsigned long long* g_cand = (unsigned long long*)(ws + WS_CAND_OFF);
    unsigned long long* g_sort = (unsigned long long*)(ws + WS_SORT_OFF);
    float4* g_sbox             = (float4*)(ws + WS_SBOX_OFF);
    int* g_keep                = (int*)(ws + WS_KEEP_OFF);
    int* g_meta                = (int*)(ws + WS_META_OFF);

    int top_k = out_size / 8;
    if (top_k > MAX_TOPK) top_k = MAX_TOPK;

    decode_kernel<<<N_BOX / 256, 256, 0, stream>>>(x, y, anchors, boxes, keys);
    select_kernel<<<1, NT, 0, stream>>>(keys, g_cand, g_meta);
    sortgather_kernel<<<1, NT, 0, stream>>>(g_cand, boxes, g_sort, g_sbox, g_meta);
    nms_kernel<<<1, 64, 0, stream>>>(g_sort, g_sbox, g_keep, g_meta, top_k);
    output_kernel<<<1, NT, 0, stream>>>(x, y, anchors, g_keep, g_meta, out, top_k);
}